// Round 5
// baseline (1617.244 us; speedup 1.0000x reference)
//
#include <hip/hip_runtime.h>

// RSSM fused forward — R4: register-resident dense weights.
// R3 post-mortem: 160 scalar LDS weight reads/lane/iter saturated the LDS pipe
// (8 waves x 160 x 5.8cy ~= entire 7125cy wall). Fix: each lane's fixed weight
// rows (Whh rowA/rowB, dyn, enc) live in VGPRs -> dense dots are pure-register
// FMAs. LDS keeps only runtime-indexed data: Wih (sparse z cols, wave-uniform
// col -> conflict-free), dec/rew/con block (12 rows, 2-way=free), h exchange.
// 512 blocks x 256 threads, each wave owns one batch element; no t-loop barriers.
// VGPR ~240 with __launch_bounds__(256,2) -> 2 waves/SIMD (8/CU), LDS ~32KB.

#define TT 256
#define NB 2048
#define HH 32
#define ZD 64
#define XDm 10
#define ADm 4

#define SWIH_S 97   // transposed [col][row], odd stride
#define SDEC_S 100  // 16B-aligned rows; 12 lanes -> 2-way start-bank (free)
#define SH_S   40

// output offsets (floats) in return order: x_logits, r_loc, c_logits, zpl, zpo
#define OFF_X   0ul
#define OFF_R   5242880ul
#define OFF_C   5767168ul
#define OFF_ZPL 6291456ul
#define OFF_ZPO 39845888ul

__device__ __forceinline__ float sigmoid_f(float v) { return 1.f / (1.f + __expf(-v)); }
__device__ __forceinline__ void nt_store(float* p, float v) { __builtin_nontemporal_store(v, p); }

extern "C" __global__ void __launch_bounds__(256, 2)
rssm_fused(const float* __restrict__ x, const float* __restrict__ a,
           const float* __restrict__ h0, const float* __restrict__ gum,
           const float* __restrict__ encW, const float* __restrict__ encB,
           const float* __restrict__ Wih, const float* __restrict__ Whh,
           const float* __restrict__ bih, const float* __restrict__ bhh,
           const float* __restrict__ decW, const float* __restrict__ decB,
           const float* __restrict__ dynW, const float* __restrict__ dynB,
           const float* __restrict__ rewW, const float* __restrict__ conW,
           const float* __restrict__ conB, float* __restrict__ out)
{
    __shared__ float sWih[68 * SWIH_S];            // 26.4 KB, transposed [col][row]
    __shared__ __align__(16) float sDec[12 * SDEC_S]; // 4.8 KB: dec rows 0..9, rew=10, con=11
    __shared__ __align__(16) float sH[4 * SH_S];   // per-wave h exchange

    const int tid = threadIdx.x;
    const int wv  = tid >> 6;       // wave in block = element slot 0..3
    const int l   = tid & 63;       // lane
    const int j32 = l & 31;
    const int grp = l >> 3;         // softmax group 0..7
    const int gl  = l & 7;          // class within group
    const int n   = blockIdx.x * 4 + wv;

    // ---- stage runtime-indexed weights into LDS (cooperative, once) ----
    for (int i = tid; i < 96 * 68; i += 256) { int j = i / 68, c = i - j * 68; sWih[c * SWIH_S + j] = Wih[i]; }
    for (int i = tid; i < 10 * 96; i += 256) { int j = i / 96, c = i - j * 96; sDec[j * SDEC_S + c] = decW[i]; }
    if (tid < 32) sDec[10 * SDEC_S + tid] = rewW[tid];
    else if (tid < 64) sDec[11 * SDEC_S + (tid - 32)] = conW[tid - 32];

    // ---- per-lane register weight rows (dense dots never touch LDS) ----
    float wA[HH], wB[HH], wD[HH], wE[42];
    {
        const int rB = 64 + j32;
#pragma unroll
        for (int k = 0; k < HH; k += 4) {
            float4 va = *(const float4*)&Whh[l * HH + k];
            wA[k] = va.x; wA[k + 1] = va.y; wA[k + 2] = va.z; wA[k + 3] = va.w;
            float4 vb = *(const float4*)&Whh[rB * HH + k];
            wB[k] = vb.x; wB[k + 1] = vb.y; wB[k + 2] = vb.z; wB[k + 3] = vb.w;
            float4 vd = *(const float4*)&dynW[l * HH + k];
            wD[k] = vd.x; wD[k + 1] = vd.y; wD[k + 2] = vd.z; wD[k + 3] = vd.w;
        }
#pragma unroll
        for (int m = 0; m < 42; m += 2) {
            float2 v = *(const float2*)&encW[l * 42 + m];
            wE[m] = v.x; wE[m + 1] = v.y;
        }
    }
    const float bihA = bih[l], bhhA = bhh[l];
    const float bihB = bih[64 + j32], bhhB = bhh[64 + j32];
    const float eB = encB[l], dB_ = dynB[l];
    float decB_l = 0.f;
    if (l < XDm) decB_l = decB[l];
    else if (l == 11) decB_l = conB[0];

    __syncthreads();   // LDS weights ready — the ONLY block barrier

    // ---- per-wave h0 init (wave-private LDS broadcast) ----
    float h[HH], h_own;
    {
        float h0v = 0.f;
        if (l < HH) { h0v = h0[(size_t)n * HH + l]; sH[wv * SH_S + l] = h0v; }
#pragma unroll
        for (int k = 0; k < HH; k += 4) {
            float4 v = *(const float4*)&sH[wv * SH_S + k];
            h[k] = v.x; h[k + 1] = v.y; h[k + 2] = v.z; h[k + 3] = v.w;
        }
        h_own = h0v;   // valid for l<32 (the only lanes that store hn back)
    }

    const float* xb = x + (size_t)n * XDm;
    const float* ab = a + (size_t)n * ADm;

    // ---- prime input pipeline: t=0 ----
    float et[XDm], ap[ADm], gv;
    float sv[8]; int si[8];
#pragma unroll
    for (int s = 0; s < 8; ++s) { sv[s] = 0.f; si[s] = 0; }
#pragma unroll
    for (int m = 0; m < XDm; ++m) et[m] = xb[m];
    gv = gum[(size_t)n * ZD + l];
#pragma unroll
    for (int m = 0; m < ADm; ++m) ap[m] = 0.f;

#pragma unroll 1
    for (int t = 0; t < TT; ++t) {
        // ---- prefetch t+1 inputs (hides HBM/L2 latency under this iteration) ----
        float etn[XDm], apn[ADm], gvn = 0.f;
        if (t + 1 < TT) {
            const float* xp = xb + (size_t)(t + 1) * (NB * XDm);
#pragma unroll
            for (int m = 0; m < XDm; ++m) etn[m] = xp[m];
            gvn = gum[((size_t)(t + 1) * NB + n) * ZD + l];
            const float* app = ab + (size_t)t * (NB * ADm);   // a[t] feeds GRU at t+1
#pragma unroll
            for (int m = 0; m < ADm; ++m) apn[m] = app[m];
        } else {
#pragma unroll
            for (int m = 0; m < XDm; ++m) etn[m] = 0.f;
#pragma unroll
            for (int m = 0; m < ADm; ++m) apn[m] = 0.f;
        }

        // ---- GRU step (t>=1): rowA = l (r/z rows), rowB = 64+(l&31) (n row) ----
        if (t > 0) {
            float accA = 0.f, accB = 0.f;
#pragma unroll
            for (int k = 0; k < HH; ++k) {
                accA = fmaf(wA[k], h[k], accA);
                accB = fmaf(wB[k], h[k], accB);
            }
            float giA = 0.f, giB = 0.f;
#pragma unroll
            for (int s = 0; s < 8; ++s) {          // sparse z part, ascending cols
                int   c = 8 * s + si[s];
                float v = sv[s];
                const float* wc = &sWih[c * SWIH_S];
                giA = fmaf(wc[l], v, giA);
                giB = fmaf(wc[64 + j32], v, giB);
            }
#pragma unroll
            for (int m = 0; m < ADm; ++m) {        // action part
                const float* wc = &sWih[(64 + m) * SWIH_S];
                giA = fmaf(wc[l], ap[m], giA);
                giB = fmaf(wc[64 + j32], ap[m], giB);
            }
            giA += bihA;  float ghA = accA + bhhA;
            giB += bihB;  float ghB = accB + bhhB;
            float sA = sigmoid_f(giA + ghA);       // r_j on l<32, z_j on l>=32
            float zj = __shfl(sA, l | 32);         // z_j delivered to all lanes
            float ng = tanhf(giB + sA * ghB);      // valid where sA==r (l<32)
            float hn = (1.f - zj) * ng + zj * h_own;
            if (l < HH) sH[wv * SH_S + l] = hn;
#pragma unroll
            for (int k = 0; k < HH; k += 4) {
                float4 v = *(const float4*)&sH[wv * SH_S + k];
                h[k] = v.x; h[k + 1] = v.y; h[k + 2] = v.z; h[k + 3] = v.w;
            }
            h_own = hn;
        }

        // ---- encoder row l: zl[l] = enc_W[l] . [h ; e_t] + enc_b[l] (pure regs) ----
        float z;
        {
            float acc = 0.f;
#pragma unroll
            for (int k = 0; k < HH; ++k) acc = fmaf(wE[k], h[k], acc);
#pragma unroll
            for (int m = 0; m < XDm; ++m) acc = fmaf(wE[HH + m], et[m], acc);
            z = acc + eB;
        }

        // ---- straight-through gumbel sample, 8-lane groups (xor 1/2/4 tree) ----
        float mx = z;
#pragma unroll
        for (int d = 1; d < 8; d <<= 1) mx = fmaxf(mx, __shfl_xor(mx, d));
        float key = z + gv; int ki = gl;
#pragma unroll
        for (int d = 1; d < 8; d <<= 1) {
            float ok = __shfl_xor(key, d); int oi = __shfl_xor(ki, d);
            if (ok > key || (ok == key && oi < ki)) { key = ok; ki = oi; }
        }
        float p = __expf(z - mx);
        float ssum = p;
#pragma unroll
        for (int d = 1; d < 8; d <<= 1) ssum += __shfl_xor(ssum, d);
        float pk  = __shfl(p, (grp << 3) + ki) / ssum;   // prob at argmax slot
        float val = pk + (1.f - pk);
#pragma unroll
        for (int s = 0; s < 8; ++s) {                    // broadcast all groups' (idx,val)
            sv[s] = __shfl(val, s << 3);
            si[s] = __shfl(ki,  s << 3);
        }

        // ---- z prior logits out (coalesced 256B per wave) ----
        nt_store(&out[OFF_ZPL + ((size_t)t * NB + n) * ZD + l], z);

        // ---- dynamics head row l (pure regs) ----
        {
            float acc = 0.f;
#pragma unroll
            for (int k = 0; k < HH; ++k) acc = fmaf(wD[k], h[k], acc);
            nt_store(&out[OFF_ZPO + ((size_t)t * NB + n) * ZD + l], acc + dB_);
        }

        // ---- decoder (rows 0..9) / reward (10) / continue (11) from LDS block ----
        if (l < 12) {
            const float* dw = &sDec[l * SDEC_S];
            float acc = 0.f;
#pragma unroll
            for (int k = 0; k < HH; k += 4) {             // h part: ds_read_b128 x8
                float4 v = *(const float4*)&dw[k];
                acc = fmaf(v.x, h[k], acc);     acc = fmaf(v.y, h[k + 1], acc);
                acc = fmaf(v.z, h[k + 2], acc); acc = fmaf(v.w, h[k + 3], acc);
            }
            if (l < XDm) {
#pragma unroll
                for (int s = 0; s < 8; ++s)               // sparse z part
                    acc = fmaf(dw[HH + 8 * s + si[s]], sv[s], acc);
                nt_store(&out[OFF_X + ((size_t)t * NB + n) * XDm + l], acc + decB_l);
            } else {
                size_t off = (l == 10) ? OFF_R : OFF_C;
                nt_store(&out[off + (size_t)t * NB + n], acc + decB_l);
            }
        }

        // ---- rotate input pipeline ----
#pragma unroll
        for (int m = 0; m < XDm; ++m) et[m] = etn[m];
#pragma unroll
        for (int m = 0; m < ADm; ++m) ap[m] = apn[m];
        gv = gvn;
    }
}

extern "C" void kernel_launch(void* const* d_in, const int* in_sizes, int n_in,
                              void* d_out, int out_size, void* d_ws, size_t ws_size,
                              hipStream_t stream) {
    const float* x    = (const float*)d_in[0];
    const float* a    = (const float*)d_in[1];
    const float* h0   = (const float*)d_in[2];
    const float* gumb = (const float*)d_in[3];
    const float* encW = (const float*)d_in[4];
    const float* encB = (const float*)d_in[5];
    const float* Wih  = (const float*)d_in[6];
    const float* Whh  = (const float*)d_in[7];
    const float* bih  = (const float*)d_in[8];
    const float* bhh  = (const float*)d_in[9];
    const float* decW = (const float*)d_in[10];
    const float* decB = (const float*)d_in[11];
    const float* dynW = (const float*)d_in[12];
    const float* dynB = (const float*)d_in[13];
    const float* rewW = (const float*)d_in[14];
    const float* conW = (const float*)d_in[15];
    const float* conB = (const float*)d_in[16];

    rssm_fused<<<NB / 4, 256, 0, stream>>>(x, a, h0, gumb, encW, encB, Wih, Whh,
                                           bih, bhh, decW, decB, dynW, dynB,
                                           rewW, conW, conB, (float*)d_out);
}